// Round 1
// baseline (76.013 us; speedup 1.0000x reference)
//
#include <hip/hip_runtime.h>

// Table-batched embedding bags: weights [T*E, D=64] f32, indices [N] local ids,
// offsets [T*B+1] ragged bag boundaries (segment s = t*B + b), out [B, T, D] f32.
// One 64-lane wave per bag; lane d owns dimension d. Each row read is 256 B
// fully coalesced. 4-way unrolled gather for memory-level parallelism.

__global__ __launch_bounds__(256) void emb_bags_kernel(
    const float* __restrict__ weights,
    const int*   __restrict__ table_offsets,
    const int*   __restrict__ indices,
    const int*   __restrict__ offsets,
    float*       __restrict__ out,
    int TB, int B, int T)
{
    const int gtid = blockIdx.x * blockDim.x + threadIdx.x;
    const int s    = gtid >> 6;          // wave id = segment id
    const int lane = threadIdx.x & 63;
    if (s >= TB) return;

    const int t = s / B;                 // table id
    const int b = s - t * B;             // batch id
    const int start = offsets[s];
    const int end   = offsets[s + 1];
    const int tbase = table_offsets[t];

    float acc0 = 0.f, acc1 = 0.f, acc2 = 0.f, acc3 = 0.f;

    int i = start;
    for (; i + 4 <= end; i += 4) {
        const int i0 = indices[i];
        const int i1 = indices[i + 1];
        const int i2 = indices[i + 2];
        const int i3 = indices[i + 3];
        const float* r0 = weights + ((long long)(tbase + i0) << 6);
        const float* r1 = weights + ((long long)(tbase + i1) << 6);
        const float* r2 = weights + ((long long)(tbase + i2) << 6);
        const float* r3 = weights + ((long long)(tbase + i3) << 6);
        // issue all four loads before any use -> 4 in flight
        const float v0 = r0[lane];
        const float v1 = r1[lane];
        const float v2 = r2[lane];
        const float v3 = r3[lane];
        acc0 += v0; acc1 += v1; acc2 += v2; acc3 += v3;
    }
    for (; i < end; ++i) {
        const int ix = indices[i];
        acc0 += weights[((long long)(tbase + ix) << 6) + lane];
    }

    const float acc = (acc0 + acc1) + (acc2 + acc3);
    // out[b, t, d] with D=64
    out[(((long long)b * T + t) << 6) + lane] = acc;
}

extern "C" void kernel_launch(void* const* d_in, const int* in_sizes, int n_in,
                              void* d_out, int out_size, void* d_ws, size_t ws_size,
                              hipStream_t stream) {
    const float* weights       = (const float*)d_in[0];
    const int*   table_offsets = (const int*)d_in[1];
    const int*   indices       = (const int*)d_in[2];
    const int*   offsets       = (const int*)d_in[3];
    float*       out           = (float*)d_out;

    const int T  = in_sizes[1];          // 8
    const int TB = in_sizes[3] - 1;      // T*B
    const int B  = TB / T;               // 2048

    const int threads = 256;             // 4 waves/block
    const int blocks  = (TB * 64 + threads - 1) / threads;
    emb_bags_kernel<<<blocks, threads, 0, stream>>>(
        weights, table_offsets, indices, offsets, out, TB, B, T);
}

// Round 2
// 52.852 us; speedup vs baseline: 1.4382x; 1.4382x over previous
//
#include <hip/hip_runtime.h>

// Table-batched embedding bags: weights [T*E, D=64] f32, indices [N] local,
// offsets [T*B+1] ragged bags (segment s = t*B + b), out [B, T, D] f32.
//
// One wave per bag. Lane = (r,c): r = lane>>4 row-slot, c = lane&15 float4
// chunk of the D=64 row. Per loop iteration the wave gathers 16 rows
// (4 row-slots x UNROLL 4) with dwordx4 loads -> 64 B/lane in flight,
// cutting both gather latency exposure and the long-bag tail 4x vs R0.

__global__ __launch_bounds__(256) void emb_bags_kernel(
    const float* __restrict__ weights,
    const int*   __restrict__ table_offsets,
    const int*   __restrict__ indices,
    const int*   __restrict__ offsets,
    float*       __restrict__ out,
    int TB, int B, int T)
{
    const int wave = (blockIdx.x * blockDim.x + threadIdx.x) >> 6;
    if (wave >= TB) return;
    const int lane = threadIdx.x & 63;
    const int c = lane & 15;   // float4 chunk within row
    const int r = lane >> 4;   // row slot 0..3

    const int t = wave / B;
    const int b = wave - t * B;
    const int start = offsets[wave];
    const int end   = offsets[wave + 1];
    const long long tbase = table_offsets[t];

    const float4* __restrict__ w4 = (const float4*)weights;

    float4 a0 = make_float4(0.f, 0.f, 0.f, 0.f);
    float4 a1 = a0, a2 = a0, a3 = a0;

    for (int i = start; i < end; i += 16) {
        const int p0 = i + r;
        const int p1 = i + 4 + r;
        const int p2 = i + 8 + r;
        const int p3 = i + 12 + r;
        // clamped index loads: always a valid address, no divergence
        const int e1 = end - 1;
        const int i0 = indices[p0 < e1 ? p0 : e1];
        const int i1 = indices[p1 < e1 ? p1 : e1];
        const int i2 = indices[p2 < e1 ? p2 : e1];
        const int i3 = indices[p3 < e1 ? p3 : e1];
        // 4 independent dwordx4 gathers in flight per lane
        const float4 v0 = w4[((size_t)(tbase + i0) << 4) + c];
        const float4 v1 = w4[((size_t)(tbase + i1) << 4) + c];
        const float4 v2 = w4[((size_t)(tbase + i2) << 4) + c];
        const float4 v3 = w4[((size_t)(tbase + i3) << 4) + c];
        if (p0 < end) { a0.x += v0.x; a0.y += v0.y; a0.z += v0.z; a0.w += v0.w; }
        if (p1 < end) { a1.x += v1.x; a1.y += v1.y; a1.z += v1.z; a1.w += v1.w; }
        if (p2 < end) { a2.x += v2.x; a2.y += v2.y; a2.z += v2.z; a2.w += v2.w; }
        if (p3 < end) { a3.x += v3.x; a3.y += v3.y; a3.z += v3.z; a3.w += v3.w; }
    }

    float4 a;
    a.x = (a0.x + a1.x) + (a2.x + a3.x);
    a.y = (a0.y + a1.y) + (a2.y + a3.y);
    a.z = (a0.z + a1.z) + (a2.z + a3.z);
    a.w = (a0.w + a1.w) + (a2.w + a3.w);

    // reduce across the 4 row-slots (lane bits 4 and 5)
    #pragma unroll
    for (int m = 16; m < 64; m <<= 1) {
        a.x += __shfl_xor(a.x, m, 64);
        a.y += __shfl_xor(a.y, m, 64);
        a.z += __shfl_xor(a.z, m, 64);
        a.w += __shfl_xor(a.w, m, 64);
    }

    if (r == 0) {
        float4* o4 = (float4*)out;
        o4[(((size_t)b * T + t) << 4) + c] = a;  // out[b, t, c*4 .. c*4+3]
    }
}

extern "C" void kernel_launch(void* const* d_in, const int* in_sizes, int n_in,
                              void* d_out, int out_size, void* d_ws, size_t ws_size,
                              hipStream_t stream) {
    const float* weights       = (const float*)d_in[0];
    const int*   table_offsets = (const int*)d_in[1];
    const int*   indices       = (const int*)d_in[2];
    const int*   offsets       = (const int*)d_in[3];
    float*       out           = (float*)d_out;

    const int T  = in_sizes[1];          // 8
    const int TB = in_sizes[3] - 1;      // T*B
    const int B  = TB / T;               // 2048

    const int threads = 256;             // 4 waves/block
    const int blocks  = (TB * 64 + threads - 1) / threads;
    emb_bags_kernel<<<blocks, threads, 0, stream>>>(
        weights, table_offsets, indices, offsets, out, TB, B, T);
}

// Round 3
// 49.161 us; speedup vs baseline: 1.5462x; 1.0751x over previous
//
#include <hip/hip_runtime.h>

// Table-batched embedding bags: weights [T*E, D=64] f32, indices [N] local,
// offsets [T*B+1] ragged bags (segment s = t*B + b), out [B, T, D] f32.
//
// One wave per bag. Lane = (r,c): r = lane>>4 row-slot, c = lane&15 float4
// chunk of the D=64 row. Slot r owns rows [i+8r, i+8r+8) of the bag, so each
// iteration gathers 32 rows with 8 independent dwordx4 loads per lane in
// flight (128 B/lane). Out-of-bag rows are exec-masked (no memory request).

__global__ __launch_bounds__(256) void emb_bags_kernel(
    const float* __restrict__ weights,
    const int*   __restrict__ table_offsets,
    const int*   __restrict__ indices,
    const int*   __restrict__ offsets,
    float*       __restrict__ out,
    int TB, int B, int T)
{
    const int wave = (blockIdx.x * blockDim.x + threadIdx.x) >> 6;
    if (wave >= TB) return;
    const int lane = threadIdx.x & 63;
    const int c = lane & 15;   // float4 chunk within row
    const int r = lane >> 4;   // row slot 0..3

    const int t = wave / B;
    const int b = wave - t * B;
    const int start = offsets[wave];
    const int end   = offsets[wave + 1];
    const long long tbase = table_offsets[t];

    const float4* __restrict__ w4 = (const float4*)weights;

    float4 a0 = make_float4(0.f, 0.f, 0.f, 0.f);
    float4 a1 = a0;

    for (int i = start; i < end; i += 32) {
        const int base = i + (r << 3);   // this slot's first row position
        const int e1   = end - 1;

        // 8 clamped index loads, all issued before any gather
        int idx[8];
        #pragma unroll
        for (int k = 0; k < 8; ++k) {
            const int p = base + k;
            idx[k] = indices[p < e1 ? p : e1];
        }

        // 8 independent gathers; masked lanes issue no request
        float4 v[8];
        #pragma unroll
        for (int k = 0; k < 8; ++k) {
            if (base + k < end) {
                v[k] = w4[((size_t)(tbase + idx[k]) << 4) + c];
            } else {
                v[k] = make_float4(0.f, 0.f, 0.f, 0.f);
            }
        }

        #pragma unroll
        for (int k = 0; k < 8; k += 2) {
            a0.x += v[k].x;     a0.y += v[k].y;
            a0.z += v[k].z;     a0.w += v[k].w;
            a1.x += v[k + 1].x; a1.y += v[k + 1].y;
            a1.z += v[k + 1].z; a1.w += v[k + 1].w;
        }
    }

    float4 a;
    a.x = a0.x + a1.x;
    a.y = a0.y + a1.y;
    a.z = a0.z + a1.z;
    a.w = a0.w + a1.w;

    // reduce across the 4 row-slots (lane bits 4 and 5)
    #pragma unroll
    for (int m = 16; m < 64; m <<= 1) {
        a.x += __shfl_xor(a.x, m, 64);
        a.y += __shfl_xor(a.y, m, 64);
        a.z += __shfl_xor(a.z, m, 64);
        a.w += __shfl_xor(a.w, m, 64);
    }

    if (r == 0) {
        float4* o4 = (float4*)out;
        o4[(((size_t)b * T + t) << 4) + c] = a;  // out[b, t, c*4 .. c*4+3]
    }
}

extern "C" void kernel_launch(void* const* d_in, const int* in_sizes, int n_in,
                              void* d_out, int out_size, void* d_ws, size_t ws_size,
                              hipStream_t stream) {
    const float* weights       = (const float*)d_in[0];
    const int*   table_offsets = (const int*)d_in[1];
    const int*   indices       = (const int*)d_in[2];
    const int*   offsets       = (const int*)d_in[3];
    float*       out           = (float*)d_out;

    const int T  = in_sizes[1];          // 8
    const int TB = in_sizes[3] - 1;      // T*B
    const int B  = TB / T;               // 2048

    const int threads = 256;             // 4 waves/block
    const int blocks  = (TB * 64 + threads - 1) / threads;
    emb_bags_kernel<<<blocks, threads, 0, stream>>>(
        weights, table_offsets, indices, offsets, out, TB, B, T);
}